// Round 5
// baseline (200.091 us; speedup 1.0000x reference)
//
#include <hip/hip_runtime.h>
#include <hip/hip_cooperative_groups.h>

namespace cg = cooperative_groups;

// Problem constants (match reference setup_inputs)
#define B_ 8
#define T_ 1024
#define S_ 4096
#define H_ 256

#define NBLK 1024
#define NTHR 256

// Fused: (A) L=-1  (B) last-covering-tag via coalesced mask stream + atomicMax
//        (C) per-wave dual-row gather + mean + seq_emb
__global__ void fused_pool_kernel(const float* __restrict__ inputs,
                                  const float* __restrict__ ttt,
                                  const float* __restrict__ seq_emb,
                                  float* __restrict__ out,
                                  int* __restrict__ L) {
    cg::grid_group grid = cg::this_grid();
    const int tid = blockIdx.x * NTHR + threadIdx.x;      // 0 .. 262143

    // ---- Phase A: L = -1 (32768 ints = 8192 int4 stores) ----
    if (tid < B_ * S_ / 4) {
        int4 m1 = {-1, -1, -1, -1};
        reinterpret_cast<int4*>(L)[tid] = m1;
    }
    grid.sync();

    // ---- Phase B: stream [B,T,S] mask in layout order; atomicMax rare positives ----
    {
        const long total4 = (long)B_ * T_ * S_ / 4;       // 8388608
        const long stride = (long)NBLK * NTHR;            // 262144 -> 32 iters
        for (long i = tid; i < total4; i += stride) {
            float4 v = reinterpret_cast<const float4*>(ttt)[i];
            long flat = i * 4;
            int s = (int)(flat & (S_ - 1));
            int t = (int)((flat >> 12) & (T_ - 1));
            int b = (int)(flat >> 22);
            int* Lrow = L + b * S_ + s;
            if (v.x > 0.0f) atomicMax(Lrow + 0, t);
            if (v.y > 0.0f) atomicMax(Lrow + 1, t);
            if (v.z > 0.0f) atomicMax(Lrow + 2, t);
            if (v.w > 0.0f) atomicMax(Lrow + 3, t);
        }
    }
    grid.sync();

    // ---- Phase C: gather. 4096 waves, each owns two consecutive rows (b,t0),(b,t1) ----
    {
        int wid  = threadIdx.x >> 6;
        int lane = threadIdx.x & 63;
        int gwave = blockIdx.x * (NTHR / 64) + wid;       // 0 .. 4095
        int bt0 = gwave * 2;                              // even -> t0 even, t1=t0+1 same b
        int b  = bt0 >> 10;
        int t0 = bt0 & (T_ - 1);
        int t1 = t0 + 1;

        const int4* Lb4 = reinterpret_cast<const int4*>(L + b * S_);
        const float4* in4 = reinterpret_cast<const float4*>(inputs);

        float4 a0 = {0.f, 0.f, 0.f, 0.f}, a1 = {0.f, 0.f, 0.f, 0.f};
        int c0 = 0, c1 = 0;

        for (int q = 0; q < S_ / 4; q += 64) {            // 16 iterations
            int4 v = Lb4[q + lane];
            // tag t0
            unsigned long long m;
            m = __ballot(v.x == t0);
            while (m) { int l = __ffsll(m) - 1; m &= m - 1;
                float4 r = in4[(size_t)(b * S_ + (q + l) * 4 + 0) * (H_ / 4) + lane];
                a0.x += r.x; a0.y += r.y; a0.z += r.z; a0.w += r.w; c0++; }
            m = __ballot(v.y == t0);
            while (m) { int l = __ffsll(m) - 1; m &= m - 1;
                float4 r = in4[(size_t)(b * S_ + (q + l) * 4 + 1) * (H_ / 4) + lane];
                a0.x += r.x; a0.y += r.y; a0.z += r.z; a0.w += r.w; c0++; }
            m = __ballot(v.z == t0);
            while (m) { int l = __ffsll(m) - 1; m &= m - 1;
                float4 r = in4[(size_t)(b * S_ + (q + l) * 4 + 2) * (H_ / 4) + lane];
                a0.x += r.x; a0.y += r.y; a0.z += r.z; a0.w += r.w; c0++; }
            m = __ballot(v.w == t0);
            while (m) { int l = __ffsll(m) - 1; m &= m - 1;
                float4 r = in4[(size_t)(b * S_ + (q + l) * 4 + 3) * (H_ / 4) + lane];
                a0.x += r.x; a0.y += r.y; a0.z += r.z; a0.w += r.w; c0++; }
            // tag t1
            m = __ballot(v.x == t1);
            while (m) { int l = __ffsll(m) - 1; m &= m - 1;
                float4 r = in4[(size_t)(b * S_ + (q + l) * 4 + 0) * (H_ / 4) + lane];
                a1.x += r.x; a1.y += r.y; a1.z += r.z; a1.w += r.w; c1++; }
            m = __ballot(v.y == t1);
            while (m) { int l = __ffsll(m) - 1; m &= m - 1;
                float4 r = in4[(size_t)(b * S_ + (q + l) * 4 + 1) * (H_ / 4) + lane];
                a1.x += r.x; a1.y += r.y; a1.z += r.z; a1.w += r.w; c1++; }
            m = __ballot(v.z == t1);
            while (m) { int l = __ffsll(m) - 1; m &= m - 1;
                float4 r = in4[(size_t)(b * S_ + (q + l) * 4 + 2) * (H_ / 4) + lane];
                a1.x += r.x; a1.y += r.y; a1.z += r.z; a1.w += r.w; c1++; }
            m = __ballot(v.w == t1);
            while (m) { int l = __ffsll(m) - 1; m &= m - 1;
                float4 r = in4[(size_t)(b * S_ + (q + l) * 4 + 3) * (H_ / 4) + lane];
                a1.x += r.x; a1.y += r.y; a1.z += r.z; a1.w += r.w; c1++; }
        }

        float inv0 = (c0 > 0) ? (1.0f / (float)c0) : 0.0f;
        float inv1 = (c1 > 0) ? (1.0f / (float)c1) : 0.0f;
        float4 e0 = reinterpret_cast<const float4*>(seq_emb)[t0 * (H_ / 4) + lane];
        float4 e1 = reinterpret_cast<const float4*>(seq_emb)[t1 * (H_ / 4) + lane];
        float4 o0, o1;
        o0.x = a0.x * inv0 + e0.x; o0.y = a0.y * inv0 + e0.y;
        o0.z = a0.z * inv0 + e0.z; o0.w = a0.w * inv0 + e0.w;
        o1.x = a1.x * inv1 + e1.x; o1.y = a1.y * inv1 + e1.y;
        o1.z = a1.z * inv1 + e1.z; o1.w = a1.w * inv1 + e1.w;
        reinterpret_cast<float4*>(out)[(size_t)bt0 * (H_ / 4) + lane] = o0;
        reinterpret_cast<float4*>(out)[(size_t)(bt0 + 1) * (H_ / 4) + lane] = o1;
    }
}

extern "C" void kernel_launch(void* const* d_in, const int* in_sizes, int n_in,
                              void* d_out, int out_size, void* d_ws, size_t ws_size,
                              hipStream_t stream) {
    const float* inputs  = (const float*)d_in[0];   // [B,S,H]
    const float* ttt     = (const float*)d_in[1];   // [B,T,S]
    const float* seq_emb = (const float*)d_in[2];   // [T,H]
    float* out = (float*)d_out;                     // [B,T,H]
    int* L = (int*)d_ws;                            // B*S ints (128 KiB)

    void* args[] = {(void*)&inputs, (void*)&ttt, (void*)&seq_emb, (void*)&out, (void*)&L};
    hipLaunchCooperativeKernel((void*)fused_pool_kernel, dim3(NBLK), dim3(NTHR),
                               args, 0, stream);
}

// Round 6
// 34.177 us; speedup vs baseline: 5.8546x; 5.8546x over previous
//
#include <hip/hip_runtime.h>

// Problem constants (match reference setup_inputs)
#define B_ 8
#define T_ 1024
#define S_ 4096
#define H_ 256

#define STRIP 128          // tokens per K1 block
#define K1_WAVES 8         // waves per K1 block; each owns T_/K1_WAVES = 128 tags

// K1: deterministic column-max (no init, no atomics).
// Block -> (b, 128-token strip). Wave w scans t in [128w, 128w+128) with
// float2-per-lane coalesced loads (512B/wave request), ascending-overwrite
// tracks the largest covered t per token. LDS 8-way max across waves, then
// unconditional int2 store of L[b, strip]. Unroll-16 keeps ~8KB/wave in
// flight (BDP ~2.4MB across 2048 waves -> BW-bound).
__global__ void __launch_bounds__(512) colmax_kernel(const float* __restrict__ ttt,
                                                     int* __restrict__ L) {
    __shared__ int red[K1_WAVES][STRIP];
    int b  = blockIdx.x >> 5;                 // 32 strips per batch
    int s0 = (blockIdx.x & 31) * STRIP;
    int w    = threadIdx.x >> 6;
    int lane = threadIdx.x & 63;
    const int tbase = w * (T_ / K1_WAVES);    // 128 tags per wave

    const float* base = ttt + ((size_t)(b * T_ + tbase) * S_) + s0 + lane * 2;
    int b0 = -1, b1 = -1;

    for (int ti = 0; ti < T_ / K1_WAVES; ti += 16) {
        float2 v[16];
#pragma unroll
        for (int j = 0; j < 16; ++j)
            v[j] = *reinterpret_cast<const float2*>(base + (size_t)(ti + j) * S_);
#pragma unroll
        for (int j = 0; j < 16; ++j) {
            int t = tbase + ti + j;
            if (v[j].x > 0.0f) b0 = t;        // ascending t -> overwrite = max
            if (v[j].y > 0.0f) b1 = t;
        }
    }
    red[w][lane * 2]     = b0;
    red[w][lane * 2 + 1] = b1;
    __syncthreads();

    if (w == 0) {                             // 64 lanes finalize 128 tokens
        int m0 = red[0][lane * 2],     m1 = red[0][lane * 2 + 1];
#pragma unroll
        for (int k = 1; k < K1_WAVES; ++k) {
            m0 = max(m0, red[k][lane * 2]);
            m1 = max(m1, red[k][lane * 2 + 1]);
        }
        int2 o = {m0, m1};
        reinterpret_cast<int2*>(L + b * S_ + s0)[lane] = o;
    }
}

// K2: gather + mean + seq_emb, fused (proven in R4, absmax 0.0).
// One wave per (b,t) output row; scans L[b,:] with int4 loads (256 tokens per
// iteration via 4 ballots); each matching token contributes a coalesced
// float4-per-lane row of inputs. No atomics.
__global__ void gather_mean_kernel(const float* __restrict__ inputs,
                                   const int* __restrict__ L,
                                   const float* __restrict__ seq_emb,
                                   float* __restrict__ out) {
    int wid  = threadIdx.x >> 6;
    int lane = threadIdx.x & 63;
    int bt = blockIdx.x * 4 + wid;               // (b*T + t), 4 waves per block
    int b = bt >> 10;                            // / T_
    int t = bt & (T_ - 1);

    const int4* Lb4 = reinterpret_cast<const int4*>(L + b * S_);
    const float4* in4 = reinterpret_cast<const float4*>(inputs);

    float4 acc = {0.0f, 0.0f, 0.0f, 0.0f};
    int c = 0;

#pragma unroll 4
    for (int c0 = 0; c0 < S_ / 4; c0 += 64) {    // int4 index space
        int4 v = Lb4[c0 + lane];
        unsigned long long m0 = __ballot(v.x == t);
        unsigned long long m1 = __ballot(v.y == t);
        unsigned long long m2 = __ballot(v.z == t);
        unsigned long long m3 = __ballot(v.w == t);
        while (m0) { int l = __ffsll(m0) - 1; m0 &= m0 - 1;
            int s = (c0 + l) * 4 + 0;
            float4 r = in4[(size_t)(b * S_ + s) * (H_ / 4) + lane];
            acc.x += r.x; acc.y += r.y; acc.z += r.z; acc.w += r.w; c++; }
        while (m1) { int l = __ffsll(m1) - 1; m1 &= m1 - 1;
            int s = (c0 + l) * 4 + 1;
            float4 r = in4[(size_t)(b * S_ + s) * (H_ / 4) + lane];
            acc.x += r.x; acc.y += r.y; acc.z += r.z; acc.w += r.w; c++; }
        while (m2) { int l = __ffsll(m2) - 1; m2 &= m2 - 1;
            int s = (c0 + l) * 4 + 2;
            float4 r = in4[(size_t)(b * S_ + s) * (H_ / 4) + lane];
            acc.x += r.x; acc.y += r.y; acc.z += r.z; acc.w += r.w; c++; }
        while (m3) { int l = __ffsll(m3) - 1; m3 &= m3 - 1;
            int s = (c0 + l) * 4 + 3;
            float4 r = in4[(size_t)(b * S_ + s) * (H_ / 4) + lane];
            acc.x += r.x; acc.y += r.y; acc.z += r.z; acc.w += r.w; c++; }
    }

    float inv = (c > 0) ? (1.0f / (float)c) : 0.0f;   // empty row -> just emb
    float4 e = reinterpret_cast<const float4*>(seq_emb)[t * (H_ / 4) + lane];
    float4 o;
    o.x = acc.x * inv + e.x;
    o.y = acc.y * inv + e.y;
    o.z = acc.z * inv + e.z;
    o.w = acc.w * inv + e.w;
    reinterpret_cast<float4*>(out)[(size_t)bt * (H_ / 4) + lane] = o;
}

extern "C" void kernel_launch(void* const* d_in, const int* in_sizes, int n_in,
                              void* d_out, int out_size, void* d_ws, size_t ws_size,
                              hipStream_t stream) {
    const float* inputs  = (const float*)d_in[0];   // [B,S,H]
    const float* ttt     = (const float*)d_in[1];   // [B,T,S]
    const float* seq_emb = (const float*)d_in[2];   // [T,H]
    float* out = (float*)d_out;                     // [B,T,H]
    int* L = (int*)d_ws;                            // B*S ints (128 KiB)

    // K1: deterministic column-max -> L  (256 blocks = 1/CU, 8 waves each)
    colmax_kernel<<<B_ * (S_ / STRIP), 512, 0, stream>>>(ttt, L);

    // K2: fused gather + mean + emb  (B*T/4 blocks, 1 wave per output row)
    gather_mean_kernel<<<B_ * T_ / 4, 256, 0, stream>>>(inputs, L, seq_emb, out);
}

// Round 7
// 30.524 us; speedup vs baseline: 6.5551x; 1.1196x over previous
//
#include <hip/hip_runtime.h>

// Problem constants (match reference setup_inputs)
#define B_ 8
#define T_ 1024
#define S_ 4096
#define H_ 256

#define STRIP 64           // tokens per K1 block
#define CHUNK 128          // tag rows per early-exit check

// K1: deterministic column-max with top-down early exit + LPT block ordering.
// Block -> (b, 64-token strip). Scans tag rows top-down in 128-row chunks
// (wave w owns 32 rows/chunk; lane owns one token; 256B coalesced row loads).
// After each chunk: LDS max-combine into best[]; if every token in the strip
// has found a covering tag, lower rows cannot change the max -> break.
// blockIdx is ordered most-expensive-first (strippos-major): hardware dispatch
// then approximates LPT scheduling, so early exits translate into makespan.
__global__ void __launch_bounds__(256) colmax_lpt_kernel(const float* __restrict__ ttt,
                                                         int* __restrict__ L) {
    __shared__ int red[4][STRIP];
    __shared__ int best[STRIP];
    __shared__ int nf;
    const int strippos = blockIdx.x >> 3;   // 0..63, low s0 (expensive) first
    const int b  = blockIdx.x & 7;
    const int s0 = strippos * STRIP;
    const int w    = threadIdx.x >> 6;
    const int lane = threadIdx.x & 63;
    const int tid  = threadIdx.x;

    if (tid < STRIP) best[tid] = -1;        // only thread tid touches best[tid]

    const float* colbase = ttt + (size_t)b * T_ * S_ + s0 + lane;

    for (int thi = T_; thi > 0; thi -= CHUNK) {
        const int t0 = thi - CHUNK + w * 32;            // wave's 32 rows
        const float* p = colbase + (size_t)t0 * S_;
        int lm = -1;
#pragma unroll
        for (int hh = 0; hh < 2; ++hh) {
            float v[16];
#pragma unroll
            for (int j = 0; j < 16; ++j)
                v[j] = p[(size_t)(hh * 16 + j) * S_];
#pragma unroll
            for (int j = 0; j < 16; ++j)
                if (v[j] > 0.0f) lm = t0 + hh * 16 + j; // ascending -> max
        }
        red[w][lane] = lm;
        __syncthreads();
        if (tid == 0) nf = 0;
        __syncthreads();
        if (tid < STRIP) {
            int m = max(max(red[0][tid], red[1][tid]),
                        max(red[2][tid], red[3][tid]));
            int bb = max(best[tid], m);
            best[tid] = bb;
            if (bb < 0) atomicOr(&nf, 1);
        }
        __syncthreads();
        if (nf == 0) break;                 // all tokens found -> done
    }

    if (tid < STRIP) L[b * S_ + s0 + tid] = best[tid];
}

// K2: gather + mean + seq_emb, fused (proven in R4/R6, absmax 0.0).
// One wave per (b,t) output row; scans L[b,:] with int4 loads (256 tokens per
// iteration via 4 ballots); each matching token contributes a coalesced
// float4-per-lane row of inputs. No atomics.
__global__ void gather_mean_kernel(const float* __restrict__ inputs,
                                   const int* __restrict__ L,
                                   const float* __restrict__ seq_emb,
                                   float* __restrict__ out) {
    int wid  = threadIdx.x >> 6;
    int lane = threadIdx.x & 63;
    int bt = blockIdx.x * 4 + wid;               // (b*T + t), 4 waves per block
    int b = bt >> 10;                            // / T_
    int t = bt & (T_ - 1);

    const int4* Lb4 = reinterpret_cast<const int4*>(L + b * S_);
    const float4* in4 = reinterpret_cast<const float4*>(inputs);

    float4 acc = {0.0f, 0.0f, 0.0f, 0.0f};
    int c = 0;

#pragma unroll 4
    for (int c0 = 0; c0 < S_ / 4; c0 += 64) {    // int4 index space
        int4 v = Lb4[c0 + lane];
        unsigned long long m0 = __ballot(v.x == t);
        unsigned long long m1 = __ballot(v.y == t);
        unsigned long long m2 = __ballot(v.z == t);
        unsigned long long m3 = __ballot(v.w == t);
        while (m0) { int l = __ffsll(m0) - 1; m0 &= m0 - 1;
            int s = (c0 + l) * 4 + 0;
            float4 r = in4[(size_t)(b * S_ + s) * (H_ / 4) + lane];
            acc.x += r.x; acc.y += r.y; acc.z += r.z; acc.w += r.w; c++; }
        while (m1) { int l = __ffsll(m1) - 1; m1 &= m1 - 1;
            int s = (c0 + l) * 4 + 1;
            float4 r = in4[(size_t)(b * S_ + s) * (H_ / 4) + lane];
            acc.x += r.x; acc.y += r.y; acc.z += r.z; acc.w += r.w; c++; }
        while (m2) { int l = __ffsll(m2) - 1; m2 &= m2 - 1;
            int s = (c0 + l) * 4 + 2;
            float4 r = in4[(size_t)(b * S_ + s) * (H_ / 4) + lane];
            acc.x += r.x; acc.y += r.y; acc.z += r.z; acc.w += r.w; c++; }
        while (m3) { int l = __ffsll(m3) - 1; m3 &= m3 - 1;
            int s = (c0 + l) * 4 + 3;
            float4 r = in4[(size_t)(b * S_ + s) * (H_ / 4) + lane];
            acc.x += r.x; acc.y += r.y; acc.z += r.z; acc.w += r.w; c++; }
    }

    float inv = (c > 0) ? (1.0f / (float)c) : 0.0f;   // empty row -> just emb
    float4 e = reinterpret_cast<const float4*>(seq_emb)[t * (H_ / 4) + lane];
    float4 o;
    o.x = acc.x * inv + e.x;
    o.y = acc.y * inv + e.y;
    o.z = acc.z * inv + e.z;
    o.w = acc.w * inv + e.w;
    reinterpret_cast<float4*>(out)[(size_t)bt * (H_ / 4) + lane] = o;
}

extern "C" void kernel_launch(void* const* d_in, const int* in_sizes, int n_in,
                              void* d_out, int out_size, void* d_ws, size_t ws_size,
                              hipStream_t stream) {
    const float* inputs  = (const float*)d_in[0];   // [B,S,H]
    const float* ttt     = (const float*)d_in[1];   // [B,T,S]
    const float* seq_emb = (const float*)d_in[2];   // [T,H]
    float* out = (float*)d_out;                     // [B,T,H]
    int* L = (int*)d_ws;                            // B*S ints (128 KiB)

    // K1: top-down early-exit column-max, expensive strips dispatched first
    colmax_lpt_kernel<<<B_ * (S_ / STRIP), 256, 0, stream>>>(ttt, L);

    // K2: fused gather + mean + emb  (B*T/4 blocks, 1 wave per output row)
    gather_mean_kernel<<<B_ * T_ / 4, 256, 0, stream>>>(inputs, L, seq_emb, out);
}